// Round 1
// baseline (28.917 us; speedup 1.0000x reference)
//
#include <hip/hip_runtime.h>

// IntervalTimeEncoder:
//   diff = ts[:,1:] - ts[:,:-1]                       [B, L]
//   idx  = clamp(floor(diff / PER_TIME), 0, 511)       (relu + JAX gather-clamp)
//   out0 = W[idx] + b                                  [B, L, 64] f32
//   out1 = ts[:, :-1]                                  [B, L]     f32
// d_in: [0]=input (int32, UNUSED), [1]=timestamp f32 [B, L+1], [2]=W f32 [512,64], [3]=b f32 [64]
// d_out: out0 (B*L*64 floats) then out1 (B*L floats), concatenated flat.

#define B_DIM 64
#define L_DIM 8192
#define TIME_DIM 64
#define N_TI 512

__global__ __launch_bounds__(256) void IntervalTimeEncoder_77653008712021_kernel(
    const float* __restrict__ ts,     // [B, L+1]
    const float* __restrict__ W,      // [512, 64]
    const float* __restrict__ bias,   // [64]
    float* __restrict__ emb,          // [B, L, 64]
    float* __restrict__ ts_out)       // [B, L]
{
    const int tid = blockIdx.x * blockDim.x + threadIdx.x;   // 0 .. B*L*16-1
    const int row = tid >> 4;          // flat (b, l) index, 0 .. B*L-1
    const int d4  = tid & 15;          // which float4 of the 64-dim embedding
    const int b   = row >> 13;         // / L_DIM (8192 = 2^13)
    const int l   = row & (L_DIM - 1);

    const int ts_base = b * (L_DIM + 1) + l;
    const float t0 = ts[ts_base];
    const float t1 = ts[ts_base + 1];

    // bit-match jnp: f32 subtract, f32 divide by 1953.125, floor, relu(int), gather-clamp
    const float diff = t1 - t0;
    int idx = (int)floorf(diff / 1953.125f);
    idx = idx < 0 ? 0 : idx;
    idx = idx > (N_TI - 1) ? (N_TI - 1) : idx;

    const float4 w  = reinterpret_cast<const float4*>(W)[idx * (TIME_DIM / 4) + d4];
    const float4 bb = reinterpret_cast<const float4*>(bias)[d4];
    float4 o;
    o.x = w.x + bb.x;
    o.y = w.y + bb.y;
    o.z = w.z + bb.z;
    o.w = w.w + bb.w;
    reinterpret_cast<float4*>(emb)[row * (TIME_DIM / 4) + d4] = o;

    if (d4 == 0) {
        ts_out[row] = t0;   // timestamp[:, :-1]
    }
}

extern "C" void kernel_launch(void* const* d_in, const int* in_sizes, int n_in,
                              void* d_out, int out_size, void* d_ws, size_t ws_size,
                              hipStream_t stream) {
    (void)in_sizes; (void)n_in; (void)d_ws; (void)ws_size; (void)out_size;
    // d_in[0] = input (int32) — unused by the reference outputs
    const float* ts   = (const float*)d_in[1];
    const float* W    = (const float*)d_in[2];
    const float* bias = (const float*)d_in[3];

    float* emb    = (float*)d_out;                              // [B, L, 64]
    float* ts_out = (float*)d_out + (size_t)B_DIM * L_DIM * TIME_DIM;  // [B, L]

    const int total_threads = B_DIM * L_DIM * (TIME_DIM / 4);   // one thread per float4
    const int block = 256;
    const int grid  = total_threads / block;                    // 32768, exact

    IntervalTimeEncoder_77653008712021_kernel<<<grid, block, 0, stream>>>(
        ts, W, bias, emb, ts_out);
}